// Round 14
// baseline (1056.171 us; speedup 1.0000x reference)
//
#include <hip/hip_runtime.h>

#define B_    64
#define T_    64
#define V_    32000
#define E_    512
#define H_    1024
#define G4_   4096      // 4*H
#define TS_   63        // time steps actually computed
#define MROWS 4032      // TS_*B_
#define MPAD  4096
#define BH    (B_ * H_)
#define FPAD  32        // flag padding: 32 dwords = 128 B (one L3 line per flag)

typedef __attribute__((ext_vector_type(8))) short bf16x8;   // 8 bf16 = 4 VGPR
typedef __attribute__((ext_vector_type(4))) float f32x4;
typedef __attribute__((ext_vector_type(4))) unsigned int uint32x4;

__device__ __forceinline__ unsigned short bfbits(float f) {  // fp32 -> bf16 (RNE)
  union { float f; unsigned int u; } cv; cv.f = f;
  unsigned int u = cv.u;
  u += 0x7fffu + ((u >> 16) & 1u);
  return (unsigned short)(u >> 16);
}
__device__ __forceinline__ float bf2f(unsigned short h) {
  union { unsigned int u; float f; } cv; cv.u = ((unsigned int)h) << 16;
  return cv.f;
}
__device__ __forceinline__ float fsig(float x) { return 1.f / (1.f + __expf(-x)); }
__device__ __forceinline__ float ftanh(float x) {
  x = fminf(fmaxf(x, -10.f), 10.f);
  const float e = __expf(2.f * x);
  return (e - 1.f) / (e + 1.f);
}

// ---- device-coherent (sc0 sc1) accesses: bypass the non-coherent per-XCD L2.
__device__ __forceinline__ void store_dword_dc(void* p, unsigned int v) {
  asm volatile("global_store_dword %0, %1, off sc0 sc1" :: "v"(p), "v"(v) : "memory");
}
__device__ __forceinline__ void store_b128_dc(void* p, uint32x4 v) {
  asm volatile("global_store_dwordx4 %0, %1, off sc0 sc1" :: "v"(p), "v"(v) : "memory");
}
__device__ __forceinline__ unsigned int load_dword_dc(const void* p) {
  unsigned int v;
  asm volatile("global_load_dword %0, %1, off sc0 sc1\n\ts_waitcnt vmcnt(0)"
               : "=v"(v) : "v"(p) : "memory");
  return v;
}
// non-temporal fp32 store: streaming hint -> don't retain in caches
__device__ __forceinline__ void store_dword_nt(void* p, float f) {
  union { float f; unsigned int u; } cv; cv.f = f;
  asm volatile("global_store_dword %0, %1, off nt" :: "v"(p), "v"(cv.u) : "memory");
}

// async global->LDS, 16B per lane (wave-uniform LDS base + lane*16)
__device__ __forceinline__ void gload16(const void* g, void* l) {
  __builtin_amdgcn_global_load_lds(
      (const __attribute__((address_space(1))) unsigned int*)g,
      (__attribute__((address_space(3))) unsigned int*)l, 16, 0, 0);
}

// ---------------- elementwise / init kernels ----------------

__global__ void k_cast4(const float4* __restrict__ s, ushort4* __restrict__ d, int n4) {
  int i = blockIdx.x * blockDim.x + threadIdx.x;
  const int st = gridDim.x * blockDim.x;
  for (; i < n4; i += st) {
    const float4 f = s[i];
    ushort4 v;
    v.x = bfbits(f.x); v.y = bfbits(f.y); v.z = bfbits(f.z); v.w = bfbits(f.w);
    d[i] = v;
  }
}

// all four recurrence weight mats in one launch
__global__ void k_castW(const float4* __restrict__ s0, const float4* __restrict__ s1,
                        const float4* __restrict__ s2, const float4* __restrict__ s3,
                        ushort4* __restrict__ d0, ushort4* __restrict__ d1,
                        ushort4* __restrict__ d2, ushort4* __restrict__ d3) {
  const int N0 = G4_ * E_ / 4, N1 = G4_ * H_ / 4;
  int i = blockIdx.x * 256 + threadIdx.x;
  const int st = gridDim.x * 256;
  for (; i < N0 + 3 * N1; i += st) {
    const float4* s; ushort4* d; int k;
    if (i < N0)            { s = s0; d = d0; k = i; }
    else if (i < N0 + N1)  { s = s1; d = d1; k = i - N0; }
    else if (i < N0 + 2*N1){ s = s2; d = d2; k = i - N0 - N1; }
    else                   { s = s3; d = d3; k = i - N0 - 2 * N1; }
    const float4 f = s[k];
    ushort4 v;
    v.x = bfbits(f.x); v.y = bfbits(f.y); v.z = bfbits(f.z); v.w = bfbits(f.w);
    d[k] = v;
  }
}

__global__ void k_bias2(const float* __restrict__ a0, const float* __restrict__ b0,
                        const float* __restrict__ a1, const float* __restrict__ b1,
                        float* __restrict__ o0, float* __restrict__ o1) {
  const int i = blockIdx.x * 256 + threadIdx.x;   // 32 blocks -> 8192
  if (i < G4_) o0[i] = a0[i] + b0[i];
  else         o1[i - G4_] = a1[i - G4_] + b1[i - G4_];
}

// X[m][e] = bf16(embed[captions[b][t]][e]), m = t*64+b (t<63); pad rows -> 0
__global__ void k_gather(const float* __restrict__ embed, const int* __restrict__ caps,
                         unsigned short* __restrict__ X) {
  const int i = blockIdx.x * 256 + threadIdx.x;   // 2048 blocks * 256 = MPAD*E_/4 exact
  const int m = i >> 7, e4 = i & 127;             // 128 float4 per row
  ushort4 v;
  if (m < MROWS) {
    const int t = m >> 6, b = m & 63;
    const int idx = caps[b * T_ + t];
    const float4 f = ((const float4*)embed)[(long)idx * (E_ / 4) + e4];
    v.x = bfbits(f.x); v.y = bfbits(f.y); v.z = bfbits(f.z); v.w = bfbits(f.w);
  } else {
    v = make_ushort4(0, 0, 0, 0);
  }
  ((ushort4*)X)[i] = v;
}

// h0/h1 initial slots + fp32 c0/c1 + flags + pad rows (zeropad folded in)
__global__ void k_init(const float* __restrict__ hidden, const float* __restrict__ cell,
                       unsigned short* __restrict__ H0, unsigned short* __restrict__ H1,
                       float* __restrict__ c0, float* __restrict__ c1,
                       unsigned int* __restrict__ flags) {
  const int i = blockIdx.x * 256 + threadIdx.x;   // 512 blocks -> 131072
  if (i < B_ * H_) {
    H0[i] = bfbits(hidden[i]);
    H1[i] = bfbits(hidden[B_ * H_ + i]);
    c0[i] = cell[i];
    c1[i] = cell[B_ * H_ + i];
    if (i < 192 * FPAD) flags[i] = 0u;
  } else {
    const int j = i - B_ * H_;                    // pad slot MPAD (rows 4096..4159)
    H0[(size_t)MPAD * H_ + j] = 0;
    H1[(size_t)MPAD * H_ + j] = 0;
  }
}

__global__ void k_zero_t0(float4* __restrict__ out4) {
  const int i = blockIdx.x * 256 + threadIdx.x;   // 2000 blocks -> 512000 = B_*V_/4 exact
  const int b = i / (V_ / 4), v = i - b * (V_ / 4);
  out4[(long)b * (T_ * V_ / 4) + v] = make_float4(0.f, 0.f, 0.f, 0.f);
}

// ---------------- GEMM1: 256^2 tile port of the proven k_gemm3 structure ----------
__global__ __launch_bounds__(512, 2) void k_gemm1(
    const unsigned short* __restrict__ A,    // [4096][512] bf16
    const unsigned short* __restrict__ Bm,   // [4096][512] bf16
    const float* __restrict__ bias,          // [4096]
    unsigned short* __restrict__ Cb) {       // [4096][4096] bf16
  __shared__ unsigned short As[2][256 * 64];   // 2 x 32 KB
  __shared__ unsigned short Bs[2][256 * 64];
  const int tid = threadIdx.x;
  const int wid = tid >> 6, l = tid & 63;
  const int wr = wid >> 2, wc = wid & 3;       // 2M x 4N wave grid
  const int lr = l & 15, khi = l >> 4;
  const long am0 = (long)blockIdx.y * 256;
  const long bn0 = (long)blockIdx.x * 256;

  int srow[4], sq[4];
  #pragma unroll
  for (int j = 0; j < 4; ++j) {
    const int idx = j * 512 + tid;
    srow[j] = idx >> 3;
    sq[j] = (idx & 7) ^ (srow[j] & 7);     // pre-swizzled source unit
  }

  f32x4 acc[8][4];
  const f32x4 z = {0.f, 0.f, 0.f, 0.f};
  #pragma unroll
  for (int mf = 0; mf < 8; ++mf)
    #pragma unroll
    for (int nf = 0; nf < 4; ++nf) acc[mf][nf] = z;

  auto stage = [&](int kt, int b) {
    const long koff = (long)kt * 128;      // BK=64 cols * 2B
    #pragma unroll
    for (int j = 0; j < 4; ++j) {
      const int idx = j * 512 + tid;
      gload16((const char*)(A + (am0 + srow[j]) * E_) + koff + sq[j] * 16,
              (char*)As[b] + idx * 16);
    }
    #pragma unroll
    for (int j = 0; j < 4; ++j) {
      const int idx = j * 512 + tid;
      gload16((const char*)(Bm + (bn0 + srow[j]) * E_) + koff + sq[j] * 16,
              (char*)Bs[b] + idx * 16);
    }
  };

  stage(0, 0);
  for (int t = 0; t < 8; ++t) {
    const int c = t & 1;
    __builtin_amdgcn_s_barrier();
    if (t + 1 < 8) {
      stage(t + 1, c ^ 1);
      asm volatile("s_waitcnt vmcnt(8)" ::: "memory");
    } else {
      asm volatile("s_waitcnt vmcnt(0)" ::: "memory");
    }
    __builtin_amdgcn_s_barrier();
    #pragma unroll
    for (int ks = 0; ks < 2; ++ks) {
      const int qx = ((ks * 4 + khi) ^ (lr & 7)) * 16;
      bf16x8 af[8], bfr[4];
      #pragma unroll
      for (int mf = 0; mf < 8; ++mf) {
        const int row = wr * 128 + mf * 16 + lr;
        af[mf] = *(const bf16x8*)((const char*)As[c] + row * 128 + qx);
      }
      #pragma unroll
      for (int nf = 0; nf < 4; ++nf) {
        const int row = wc * 64 + nf * 16 + lr;
        bfr[nf] = *(const bf16x8*)((const char*)Bs[c] + row * 128 + qx);
      }
      __builtin_amdgcn_s_setprio(1);
      #pragma unroll
      for (int mf = 0; mf < 8; ++mf)
        #pragma unroll
        for (int nf = 0; nf < 4; ++nf)
          acc[mf][nf] = __builtin_amdgcn_mfma_f32_16x16x32_bf16(af[mf], bfr[nf], acc[mf][nf], 0, 0, 0);
      __builtin_amdgcn_s_setprio(0);
    }
  }

  #pragma unroll
  for (int nf = 0; nf < 4; ++nf) {
    const int n = (int)bn0 + wc * 64 + nf * 16 + lr;
    const float bv = bias[n];
    #pragma unroll
    for (int mf = 0; mf < 8; ++mf) {
      #pragma unroll
      for (int r = 0; r < 4; ++r) {
        const int m = (int)am0 + wr * 128 + mf * 16 + khi * 4 + r;
        Cb[(long)m * G4_ + n] = bfbits(acc[mf][nf][r] + bv);
      }
    }
  }
}

// ---------------- GEMM3: logits (256x256, BK=64 2-buf, counted vmcnt) ----------------
// NEW (R14): tile decode M-FASTEST (by = id&15) so the 16 M-blocks sharing one
// B-panel run consecutively/concurrently -> B-panel L2-resident, Wp crosses HBM
// once (64 MB) instead of ~16x (~1 GB), A stays L3-resident.
__global__ __launch_bounds__(512, 2) void k_gemm3(
    const unsigned short* __restrict__ A,    // [4096][1024] bf16 (H1 slots 1..64)
    const unsigned short* __restrict__ Bm,   // [32000][1024] bf16 (Wp)
    const float* __restrict__ bias,          // [32000]
    float* __restrict__ out) {               // [64][64][32000] f32
  __shared__ unsigned short As[2][256 * 64];   // 2 x 32 KB
  __shared__ unsigned short Bs[2][256 * 64];   // 2 x 32 KB
  const int tid = threadIdx.x;
  const int wid = tid >> 6, l = tid & 63;
  const int wr = wid >> 2, wc = wid & 3;       // 2M x 4N wave grid
  const int lr = l & 15, khi = l >> 4;
  const int id = blockIdx.x;                   // 2000 = 16 M x 125 N
  const int by = id & 15, bx = id >> 4;        // M fastest: B-panel reuse is temporal-local
  const long am0 = (long)by * 256;
  const long bn0 = (long)bx * 256;

  int srow[4], sq[4];
  #pragma unroll
  for (int j = 0; j < 4; ++j) {
    const int idx = j * 512 + tid;
    srow[j] = idx >> 3;
    sq[j] = (idx & 7) ^ (srow[j] & 7);     // pre-swizzled source unit
  }

  f32x4 acc[8][4];
  const f32x4 z = {0.f, 0.f, 0.f, 0.f};
  #pragma unroll
  for (int mf = 0; mf < 8; ++mf)
    #pragma unroll
    for (int nf = 0; nf < 4; ++nf) acc[mf][nf] = z;

  auto stage = [&](int kt, int b) {
    const long koff = (long)kt * 128;      // BK=64 cols * 2B
    #pragma unroll
    for (int j = 0; j < 4; ++j) {
      const int idx = j * 512 + tid;
      gload16((const char*)(A + (am0 + srow[j]) * H_) + koff + sq[j] * 16,
              (char*)As[b] + idx * 16);
    }
    #pragma unroll
    for (int j = 0; j < 4; ++j) {
      const int idx = j * 512 + tid;
      gload16((const char*)(Bm + (bn0 + srow[j]) * H_) + koff + sq[j] * 16,
              (char*)Bs[b] + idx * 16);
    }
  };

  stage(0, 0);
  for (int t = 0; t < 16; ++t) {
    const int c = t & 1;
    __builtin_amdgcn_s_barrier();          // all waves done reading buf c from t-2
    if (t + 1 < 16) {
      stage(t + 1, c ^ 1);
      asm volatile("s_waitcnt vmcnt(8)" ::: "memory");   // tile t done; t+1 in flight
    } else {
      asm volatile("s_waitcnt vmcnt(0)" ::: "memory");
    }
    __builtin_amdgcn_s_barrier();          // tile t staged by ALL waves
    #pragma unroll
    for (int ks = 0; ks < 2; ++ks) {
      const int qx = ((ks * 4 + khi) ^ (lr & 7)) * 16;   // swizzled read unit (bytes)
      bf16x8 af[8], bfr[4];
      #pragma unroll
      for (int mf = 0; mf < 8; ++mf) {
        const int row = wr * 128 + mf * 16 + lr;
        af[mf] = *(const bf16x8*)((const char*)As[c] + row * 128 + qx);
      }
      #pragma unroll
      for (int nf = 0; nf < 4; ++nf) {
        const int row = wc * 64 + nf * 16 + lr;
        bfr[nf] = *(const bf16x8*)((const char*)Bs[c] + row * 128 + qx);
      }
      __builtin_amdgcn_s_setprio(1);
      #pragma unroll
      for (int mf = 0; mf < 8; ++mf)
        #pragma unroll
        for (int nf = 0; nf < 4; ++nf)
          acc[mf][nf] = __builtin_amdgcn_mfma_f32_16x16x32_bf16(af[mf], bfr[nf], acc[mf][nf], 0, 0, 0);
      __builtin_amdgcn_s_setprio(0);
    }
  }

  // epilogue: fp32 nt scatter to out[:,t+1,:]
  #pragma unroll
  for (int nf = 0; nf < 4; ++nf) {
    const int n = (int)bn0 + wc * 64 + nf * 16 + lr;
    const float bv = bias[n];
    #pragma unroll
    for (int mf = 0; mf < 8; ++mf) {
      #pragma unroll
      for (int r = 0; r < 4; ++r) {
        const int m = (int)am0 + wr * 128 + mf * 16 + khi * 4 + r;
        if (m < MROWS) {
          const int t = m >> 6, b = m & 63;
          store_dword_nt(out + (long)(b * T_ + t + 1) * V_ + n, acc[mf][nf][r] + bv);
        }
      }
    }
  }
}

// ---------------- fused 2-layer persistent recurrence (R8-verified lockstep) ----------
__global__ __launch_bounds__(256) void k_fused(
    const unsigned short* __restrict__ Whh0b,  // [4096][1024] bf16
    const unsigned short* __restrict__ Whh1b,  // [4096][1024] bf16
    const unsigned short* __restrict__ Wih1b,  // [4096][1024] bf16
    const unsigned short* __restrict__ Xp,     // [63][64][4096] bf16 (x-proj + b0)
    unsigned short* __restrict__ H0b,          // [65][64][1024] bf16, slot 0 init
    unsigned short* __restrict__ H1b,          // [65][64][1024] bf16, slot 0 init
    const float* __restrict__ c0i, const float* __restrict__ c1i,
    const float* __restrict__ b1s,             // [4096] f32
    unsigned int* __restrict__ f0,             // [64*FPAD]  zeroed
    unsigned int* __restrict__ f1) {           // [128*FPAD] zeroed
  __shared__ unsigned short Wl[64 * 1024];     // 128 KB
  __shared__ __align__(16) float gs1[4][64][8];  // 8 KB (team-1); aliased by team-0
  unsigned short (*hexch)[16] = (unsigned short (*)[16])gs1;

  const int tid = threadIdx.x;
  const int w = tid >> 6, l = tid & 63;
  const int lcol = l & 15, khi = l >> 4;
  const int bw = w * 16;
  const f32x4 z = {0.f, 0.f, 0.f, 0.f};

  if (blockIdx.x < 64) {
    // ================= TEAM 0 : layer 0 =================
    const int blk = blockIdx.x;
    const int jb = blk << 4;
    for (int u = tid; u < 64 * 128; u += 256) {
      const int rr = u >> 7, cu = u & 127;
      const int g = rr >> 4, jj = rr & 15;
      ((bf16x8*)Wl)[rr * 128 + (cu ^ (rr & 7))] =
          *(const bf16x8*)(Whh0b + (size_t)(g * 1024 + jb + jj) * H_ + cu * 8);
    }
    f32x4 cr;
    #pragma unroll
    for (int r = 0; r < 4; ++r)
      cr[r] = c0i[(size_t)(bw + khi * 4 + r) * H_ + jb + lcol];
    unsigned short pin[16];
    #pragma unroll
    for (int r = 0; r < 4; ++r) {
      const unsigned short* ir = Xp + (size_t)(bw + khi * 4 + r) * G4_ + jb + lcol;
      pin[r * 4 + 0] = ir[0];
      pin[r * 4 + 1] = ir[H_];
      pin[r * 4 + 2] = ir[2 * H_];
      pin[r * 4 + 3] = ir[3 * H_];
    }
    __syncthreads();

    for (int s = 0; s < TS_; ++s) {
      if (s > 0) {
        if (tid < 64)
          while (load_dword_dc(&f0[tid << 5]) < (unsigned)s) __builtin_amdgcn_s_sleep(1);
        __syncthreads();
      }
      f32x4 a0, a1, a2, a3;
      #pragma unroll
      for (int r = 0; r < 4; ++r) {
        a0[r] = bf2f(pin[r * 4 + 0]);
        a1[r] = bf2f(pin[r * 4 + 1]);
        a2[r] = bf2f(pin[r * 4 + 2]);
        a3[r] = bf2f(pin[r * 4 + 3]);
      }
      const unsigned short* hrow = H0b + (size_t)s * BH + (size_t)(bw + lcol) * H_ + khi * 8;
      #pragma unroll 8
      for (int kk = 0; kk < 32; ++kk) {
        const bf16x8 av = *(const bf16x8*)(hrow + kk * 32);
        const int un = (kk * 4 + khi) ^ (lcol & 7);
        const bf16x8 b0 = ((const bf16x8*)Wl)[(0 * 16 + lcol) * 128 + un];
        const bf16x8 b1 = ((const bf16x8*)Wl)[(1 * 16 + lcol) * 128 + un];
        const bf16x8 b2 = ((const bf16x8*)Wl)[(2 * 16 + lcol) * 128 + un];
        const bf16x8 b3 = ((const bf16x8*)Wl)[(3 * 16 + lcol) * 128 + un];
        a0 = __builtin_amdgcn_mfma_f32_16x16x32_bf16(av, b0, a0, 0, 0, 0);
        a1 = __builtin_amdgcn_mfma_f32_16x16x32_bf16(av, b1, a1, 0, 0, 0);
        a2 = __builtin_amdgcn_mfma_f32_16x16x32_bf16(av, b2, a2, 0, 0, 0);
        a3 = __builtin_amdgcn_mfma_f32_16x16x32_bf16(av, b3, a3, 0, 0, 0);
      }
      #pragma unroll
      for (int r = 0; r < 4; ++r) {
        const float gi = fsig(a0[r]);
        const float gf = fsig(a1[r]);
        const float gg = ftanh(a2[r]);
        const float go = fsig(a3[r]);
        cr[r] = gf * cr[r] + gi * gg;
        hexch[bw + khi * 4 + r][lcol] = bfbits(go * ftanh(cr[r]));
      }
      if (s + 1 < TS_) {
        const unsigned short* inb = Xp + (size_t)(s + 1) * (B_ * G4_);
        #pragma unroll
        for (int r = 0; r < 4; ++r) {
          const unsigned short* ir = inb + (size_t)(bw + khi * 4 + r) * G4_ + jb + lcol;
          pin[r * 4 + 0] = ir[0];
          pin[r * 4 + 1] = ir[H_];
          pin[r * 4 + 2] = ir[2 * H_];
          pin[r * 4 + 3] = ir[3 * H_];
        }
      }
      __syncthreads();                       // hexch complete
      if (tid < 128) {                       // coalesced 16B device-coherent stores
        const int b = tid >> 1, hf = tid & 1;
        const uint32x4 v = *(const uint32x4*)&hexch[b][hf * 8];
        store_b128_dc(H0b + (size_t)(s + 1) * BH + (size_t)b * H_ + jb + hf * 8, v);
      }
      __syncthreads();                       // drain stores (per-wave vmcnt)
      if (tid == 0) store_dword_dc(&f0[blk << 5], (unsigned)(s + 1));
    }
  } else {
    // ================= TEAM 1 : layer 1 =================
    const int blk1 = blockIdx.x - 64;
    const int jb1 = blk1 << 3;
    for (int u = tid; u < 64 * 128; u += 256) {
      const int pr = u >> 7, cu = u & 127;
      const int prl = pr & 31, tt = prl >> 4, lr_ = prl & 15;
      const int g = tt * 2 + (lr_ >> 3), jj = lr_ & 7;
      const unsigned short* src =
          ((pr >> 5) ? Wih1b : Whh1b) + (size_t)(g * 1024 + jb1 + jj) * H_ + cu * 8;
      ((bf16x8*)Wl)[pr * 128 + (cu ^ (pr & 7))] = *(const bf16x8*)src;
    }
    const int bb = tid >> 2;
    const int j0 = (tid * 2) & 7;
    float cA = c1i[(size_t)bb * H_ + jb1 + j0];
    float cB = c1i[(size_t)bb * H_ + jb1 + j0 + 1];
    float biA[4], biB[4];
    #pragma unroll
    for (int g = 0; g < 4; ++g) {
      biA[g] = b1s[g * 1024 + jb1 + j0];
      biB[g] = b1s[g * 1024 + jb1 + j0 + 1];
    }
    __syncthreads();

    for (int s = 1; s <= TS_; ++s) {
      {
        const unsigned t0 = (unsigned)s, t1 = (unsigned)(s - 1);
        if (tid < 64) {
          while (load_dword_dc(&f0[tid << 5]) < t0) __builtin_amdgcn_s_sleep(1);
        } else if (tid < 192) {
          while (load_dword_dc(&f1[(tid - 64) << 5]) < t1) __builtin_amdgcn_s_sleep(1);
        }
        __syncthreads();
      }
      f32x4 ac0 = z, ac1 = z;
      const unsigned short* a1p = H1b + (size_t)(s - 1) * BH + (size_t)(bw + lcol) * H_ + khi * 8;
      const unsigned short* a0p = H0b + (size_t)s * BH + (size_t)(bw + lcol) * H_ + khi * 8;
      #pragma unroll 8
      for (int kk = 0; kk < 32; ++kk) {
        const bf16x8 av = *(const bf16x8*)(a1p + kk * 32);
        const int un = (kk * 4 + khi) ^ (lcol & 7);
        const bf16x8 b0 = ((const bf16x8*)Wl)[(0 + lcol) * 128 + un];
        const bf16x8 b1 = ((const bf16x8*)Wl)[(16 + lcol) * 128 + un];
        ac0 = __builtin_amdgcn_mfma_f32_16x16x32_bf16(av, b0, ac0, 0, 0, 0);
        ac1 = __builtin_amdgcn_mfma_f32_16x16x32_bf16(av, b1, ac1, 0, 0, 0);
      }
      #pragma unroll 8
      for (int kk = 0; kk < 32; ++kk) {
        const bf16x8 av = *(const bf16x8*)(a0p + kk * 32);
        const int un = (kk * 4 + khi) ^ (lcol & 7);
        const bf16x8 b0 = ((const bf16x8*)Wl)[(32 + lcol) * 128 + un];
        const bf16x8 b1 = ((const bf16x8*)Wl)[(48 + lcol) * 128 + un];
        ac0 = __builtin_amdgcn_mfma_f32_16x16x32_bf16(av, b0, ac0, 0, 0, 0);
        ac1 = __builtin_amdgcn_mfma_f32_16x16x32_bf16(av, b1, ac1, 0, 0, 0);
      }
      #pragma unroll
      for (int r = 0; r < 4; ++r) {
        const int b = bw + khi * 4 + r;
        gs1[lcol >> 3][b][lcol & 7] = ac0[r];
        gs1[2 + (lcol >> 3)][b][lcol & 7] = ac1[r];
      }
      __syncthreads();
      {
        const float giA = fsig(gs1[0][bb][j0] + biA[0]);
        const float gfA = fsig(gs1[1][bb][j0] + biA[1]);
        const float ggA = ftanh(gs1[2][bb][j0] + biA[2]);
        const float goA = fsig(gs1[3][bb][j0] + biA[3]);
        cA = gfA * cA + giA * ggA;
        const unsigned short hA = bfbits(goA * ftanh(cA));
        const float giB = fsig(gs1[0][bb][j0 + 1] + biB[0]);
        const float gfB = fsig(gs1[1][bb][j0 + 1] + biB[1]);
        const float ggB = ftanh(gs1[2][bb][j0 + 1] + biB[2]);
        const float goB = fsig(gs1[3][bb][j0 + 1] + biB[3]);
        cB = gfB * cB + giB * ggB;
        const unsigned short hB = bfbits(goB * ftanh(cB));
        const unsigned int hv = ((unsigned int)hB << 16) | hA;
        store_dword_dc(H1b + (size_t)s * BH + (size_t)bb * H_ + jb1 + j0, hv);
      }
      __syncthreads();                       // drain stores + gs1 WAR protection
      if (tid == 0) store_dword_dc(&f1[blk1 << 5], (unsigned)s);
    }
  }
}

// ---------------- launch ----------------

extern "C" void kernel_launch(void* const* d_in, const int* in_sizes, int n_in,
                              void* d_out, int out_size, void* d_ws, size_t ws_size,
                              hipStream_t stream) {
  (void)in_sizes; (void)n_in; (void)out_size; (void)ws_size;
  const float* hidden = (const float*)d_in[0];
  const float* cell   = (const float*)d_in[1];
  const int*   caps   = (const int*)d_in[2];
  const float* embed  = (const float*)d_in[3];
  const float* Wih0   = (const float*)d_in[4];
  const float* Whh0   = (const float*)d_in[5];
  const float* bih0   = (const float*)d_in[6];
  const float* bhh0   = (const float*)d_in[7];
  const float* Wih1   = (const float*)d_in[8];
  const float* Whh1   = (const float*)d_in[9];
  const float* bih1   = (const float*)d_in[10];
  const float* bhh1   = (const float*)d_in[11];
  const float* Wp     = (const float*)d_in[12];
  const float* bp     = (const float*)d_in[13];
  float* out = (float*)d_out;

  // workspace layout (~150 MB)
  char* p = (char*)d_ws;
  auto alloc = [&](size_t bytes) { char* r = p; p += (bytes + 255) & ~(size_t)255; return r; };
  unsigned short* Xbf   = (unsigned short*)alloc((size_t)MPAD * E_ * 2);
  unsigned short* Wih0b = (unsigned short*)alloc((size_t)G4_ * E_ * 2);
  unsigned short* Whh0b = (unsigned short*)alloc((size_t)G4_ * H_ * 2);
  unsigned short* Wih1b = (unsigned short*)alloc((size_t)G4_ * H_ * 2);
  unsigned short* Whh1b = (unsigned short*)alloc((size_t)G4_ * H_ * 2);
  unsigned short* Wpb   = (unsigned short*)alloc((size_t)V_ * H_ * 2);
  unsigned short* Xp    = (unsigned short*)alloc((size_t)MPAD * G4_ * 2);
  unsigned short* H0    = (unsigned short*)alloc((size_t)(MPAD + B_) * H_ * 2);  // slots 0..64
  unsigned short* H1    = (unsigned short*)alloc((size_t)(MPAD + B_) * H_ * 2);
  float* c0  = (float*)alloc((size_t)B_ * H_ * 4);
  float* c1  = (float*)alloc((size_t)B_ * H_ * 4);
  float* b0s = (float*)alloc((size_t)G4_ * 4);
  float* b1s = (float*)alloc((size_t)G4_ * 4);
  unsigned int* cbar = (unsigned int*)alloc((size_t)192 * FPAD * 4);  // f0 | f1, padded

  k_castW<<<4096, 256, 0, stream>>>((const float4*)Wih0, (const float4*)Whh0,
                                    (const float4*)Wih1, (const float4*)Whh1,
                                    (ushort4*)Wih0b, (ushort4*)Whh0b,
                                    (ushort4*)Wih1b, (ushort4*)Whh1b);
  k_cast4<<<4096, 256, 0, stream>>>((const float4*)Wp, (ushort4*)Wpb, V_ * H_ / 4);
  k_bias2<<<32, 256, 0, stream>>>(bih0, bhh0, bih1, bhh1, b0s, b1s);
  k_gather<<<2048, 256, 0, stream>>>(embed, caps, Xbf);
  k_init<<<512, 256, 0, stream>>>(hidden, cell, H0, H1, c0, c1, cbar);
  k_zero_t0<<<2000, 256, 0, stream>>>((float4*)out);

  // GEMM1: Xp = X @ W_ih0^T + b0   (M=4096, N=4096, K=512; 256^2 proven structure)
  k_gemm1<<<dim3(16, 16), 512, 0, stream>>>(Xbf, Wih0b, b0s, Xp);

  // fused 2-layer recurrence (192 co-resident blocks, R8-verified lockstep)
  k_fused<<<192, 256, 0, stream>>>(Whh0b, Whh1b, Wih1b, Xp, H0, H1, c0, c1, b1s,
                                   cbar, cbar + 64 * FPAD);

  // GEMM3: logits = H1[1..63] @ Wp^T + bp -> out[:,1:,:]  (256^2, BK=64, M-fastest decode)
  k_gemm3<<<2000, 512, 0, stream>>>(H1 + (size_t)B_ * H_, Wpb, bp, out);
}

// Round 15
// 1039.520 us; speedup vs baseline: 1.0160x; 1.0160x over previous
//
#include <hip/hip_runtime.h>

#define B_    64
#define T_    64
#define V_    32000
#define E_    512
#define H_    1024
#define G4_   4096      // 4*H
#define TS_   63        // time steps actually computed
#define MROWS 4032      // TS_*B_
#define MPAD  4096
#define BH    (B_ * H_)
#define FPAD  32        // flag padding: 32 dwords = 128 B (one L3 line per flag)

typedef __attribute__((ext_vector_type(8))) short bf16x8;   // 8 bf16 = 4 VGPR
typedef __attribute__((ext_vector_type(4))) float f32x4;
typedef __attribute__((ext_vector_type(4))) unsigned int uint32x4;

__device__ __forceinline__ unsigned short bfbits(float f) {  // fp32 -> bf16 (RNE)
  union { float f; unsigned int u; } cv; cv.f = f;
  unsigned int u = cv.u;
  u += 0x7fffu + ((u >> 16) & 1u);
  return (unsigned short)(u >> 16);
}
__device__ __forceinline__ float bf2f(unsigned short h) {
  union { unsigned int u; float f; } cv; cv.u = ((unsigned int)h) << 16;
  return cv.f;
}
__device__ __forceinline__ float fsig(float x) { return 1.f / (1.f + __expf(-x)); }
__device__ __forceinline__ float ftanh(float x) {
  x = fminf(fmaxf(x, -10.f), 10.f);
  const float e = __expf(2.f * x);
  return (e - 1.f) / (e + 1.f);
}

// ---- device-coherent (sc0 sc1) accesses: bypass the non-coherent per-XCD L2.
__device__ __forceinline__ void store_dword_dc(void* p, unsigned int v) {
  asm volatile("global_store_dword %0, %1, off sc0 sc1" :: "v"(p), "v"(v) : "memory");
}
__device__ __forceinline__ void store_b128_dc(void* p, uint32x4 v) {
  asm volatile("global_store_dwordx4 %0, %1, off sc0 sc1" :: "v"(p), "v"(v) : "memory");
}
__device__ __forceinline__ unsigned int load_dword_dc(const void* p) {
  unsigned int v;
  asm volatile("global_load_dword %0, %1, off sc0 sc1\n\ts_waitcnt vmcnt(0)"
               : "=v"(v) : "v"(p) : "memory");
  return v;
}
// non-temporal fp32 store: streaming hint -> don't retain in caches
__device__ __forceinline__ void store_dword_nt(void* p, float f) {
  union { float f; unsigned int u; } cv; cv.f = f;
  asm volatile("global_store_dword %0, %1, off nt" :: "v"(p), "v"(cv.u) : "memory");
}

// async global->LDS, 16B per lane (wave-uniform LDS base + lane*16)
__device__ __forceinline__ void gload16(const void* g, void* l) {
  __builtin_amdgcn_global_load_lds(
      (const __attribute__((address_space(1))) unsigned int*)g,
      (__attribute__((address_space(3))) unsigned int*)l, 16, 0, 0);
}

// ---------------- elementwise / init kernels ----------------

__global__ void k_cast4(const float4* __restrict__ s, ushort4* __restrict__ d, int n4) {
  int i = blockIdx.x * blockDim.x + threadIdx.x;
  const int st = gridDim.x * blockDim.x;
  for (; i < n4; i += st) {
    const float4 f = s[i];
    ushort4 v;
    v.x = bfbits(f.x); v.y = bfbits(f.y); v.z = bfbits(f.z); v.w = bfbits(f.w);
    d[i] = v;
  }
}

// all four recurrence weight mats in one launch
__global__ void k_castW(const float4* __restrict__ s0, const float4* __restrict__ s1,
                        const float4* __restrict__ s2, const float4* __restrict__ s3,
                        ushort4* __restrict__ d0, ushort4* __restrict__ d1,
                        ushort4* __restrict__ d2, ushort4* __restrict__ d3) {
  const int N0 = G4_ * E_ / 4, N1 = G4_ * H_ / 4;
  int i = blockIdx.x * 256 + threadIdx.x;
  const int st = gridDim.x * 256;
  for (; i < N0 + 3 * N1; i += st) {
    const float4* s; ushort4* d; int k;
    if (i < N0)            { s = s0; d = d0; k = i; }
    else if (i < N0 + N1)  { s = s1; d = d1; k = i - N0; }
    else if (i < N0 + 2*N1){ s = s2; d = d2; k = i - N0 - N1; }
    else                   { s = s3; d = d3; k = i - N0 - 2 * N1; }
    const float4 f = s[k];
    ushort4 v;
    v.x = bfbits(f.x); v.y = bfbits(f.y); v.z = bfbits(f.z); v.w = bfbits(f.w);
    d[k] = v;
  }
}

__global__ void k_bias2(const float* __restrict__ a0, const float* __restrict__ b0,
                        const float* __restrict__ a1, const float* __restrict__ b1,
                        float* __restrict__ o0, float* __restrict__ o1) {
  const int i = blockIdx.x * 256 + threadIdx.x;   // 32 blocks -> 8192
  if (i < G4_) o0[i] = a0[i] + b0[i];
  else         o1[i - G4_] = a1[i - G4_] + b1[i - G4_];
}

// X[m][e] = bf16(embed[captions[b][t]][e]), m = t*64+b (t<63); pad rows -> 0
__global__ void k_gather(const float* __restrict__ embed, const int* __restrict__ caps,
                         unsigned short* __restrict__ X) {
  const int i = blockIdx.x * 256 + threadIdx.x;   // 2048 blocks * 256 = MPAD*E_/4 exact
  const int m = i >> 7, e4 = i & 127;             // 128 float4 per row
  ushort4 v;
  if (m < MROWS) {
    const int t = m >> 6, b = m & 63;
    const int idx = caps[b * T_ + t];
    const float4 f = ((const float4*)embed)[(long)idx * (E_ / 4) + e4];
    v.x = bfbits(f.x); v.y = bfbits(f.y); v.z = bfbits(f.z); v.w = bfbits(f.w);
  } else {
    v = make_ushort4(0, 0, 0, 0);
  }
  ((ushort4*)X)[i] = v;
}

// h0/h1 initial slots + fp32 c0/c1 + flags + pad rows (zeropad folded in)
__global__ void k_init(const float* __restrict__ hidden, const float* __restrict__ cell,
                       unsigned short* __restrict__ H0, unsigned short* __restrict__ H1,
                       float* __restrict__ c0, float* __restrict__ c1,
                       unsigned int* __restrict__ flags) {
  const int i = blockIdx.x * 256 + threadIdx.x;   // 512 blocks -> 131072
  if (i < B_ * H_) {
    H0[i] = bfbits(hidden[i]);
    H1[i] = bfbits(hidden[B_ * H_ + i]);
    c0[i] = cell[i];
    c1[i] = cell[B_ * H_ + i];
    if (i < 192 * FPAD) flags[i] = 0u;
  } else {
    const int j = i - B_ * H_;                    // pad slot MPAD (rows 4096..4159)
    H0[(size_t)MPAD * H_ + j] = 0;
    H1[(size_t)MPAD * H_ + j] = 0;
  }
}

__global__ void k_zero_t0(float4* __restrict__ out4) {
  const int i = blockIdx.x * 256 + threadIdx.x;   // 2000 blocks -> 512000 = B_*V_/4 exact
  const int b = i / (V_ / 4), v = i - b * (V_ / 4);
  out4[(long)b * (T_ * V_ / 4) + v] = make_float4(0.f, 0.f, 0.f, 0.f);
}

// ---------------- GEMM1: 256^2 tile port of the proven k_gemm3 structure ----------
__global__ __launch_bounds__(512, 2) void k_gemm1(
    const unsigned short* __restrict__ A,    // [4096][512] bf16
    const unsigned short* __restrict__ Bm,   // [4096][512] bf16
    const float* __restrict__ bias,          // [4096]
    unsigned short* __restrict__ Cb) {       // [4096][4096] bf16
  __shared__ unsigned short As[2][256 * 64];   // 2 x 32 KB
  __shared__ unsigned short Bs[2][256 * 64];
  const int tid = threadIdx.x;
  const int wid = tid >> 6, l = tid & 63;
  const int wr = wid >> 2, wc = wid & 3;       // 2M x 4N wave grid
  const int lr = l & 15, khi = l >> 4;
  const long am0 = (long)blockIdx.y * 256;
  const long bn0 = (long)blockIdx.x * 256;

  int srow[4], sq[4];
  #pragma unroll
  for (int j = 0; j < 4; ++j) {
    const int idx = j * 512 + tid;
    srow[j] = idx >> 3;
    sq[j] = (idx & 7) ^ (srow[j] & 7);     // pre-swizzled source unit
  }

  f32x4 acc[8][4];
  const f32x4 z = {0.f, 0.f, 0.f, 0.f};
  #pragma unroll
  for (int mf = 0; mf < 8; ++mf)
    #pragma unroll
    for (int nf = 0; nf < 4; ++nf) acc[mf][nf] = z;

  auto stage = [&](int kt, int b) {
    const long koff = (long)kt * 128;      // BK=64 cols * 2B
    #pragma unroll
    for (int j = 0; j < 4; ++j) {
      const int idx = j * 512 + tid;
      gload16((const char*)(A + (am0 + srow[j]) * E_) + koff + sq[j] * 16,
              (char*)As[b] + idx * 16);
    }
    #pragma unroll
    for (int j = 0; j < 4; ++j) {
      const int idx = j * 512 + tid;
      gload16((const char*)(Bm + (bn0 + srow[j]) * E_) + koff + sq[j] * 16,
              (char*)Bs[b] + idx * 16);
    }
  };

  stage(0, 0);
  for (int t = 0; t < 8; ++t) {
    const int c = t & 1;
    __builtin_amdgcn_s_barrier();
    if (t + 1 < 8) {
      stage(t + 1, c ^ 1);
      asm volatile("s_waitcnt vmcnt(8)" ::: "memory");
    } else {
      asm volatile("s_waitcnt vmcnt(0)" ::: "memory");
    }
    __builtin_amdgcn_s_barrier();
    #pragma unroll
    for (int ks = 0; ks < 2; ++ks) {
      const int qx = ((ks * 4 + khi) ^ (lr & 7)) * 16;
      bf16x8 af[8], bfr[4];
      #pragma unroll
      for (int mf = 0; mf < 8; ++mf) {
        const int row = wr * 128 + mf * 16 + lr;
        af[mf] = *(const bf16x8*)((const char*)As[c] + row * 128 + qx);
      }
      #pragma unroll
      for (int nf = 0; nf < 4; ++nf) {
        const int row = wc * 64 + nf * 16 + lr;
        bfr[nf] = *(const bf16x8*)((const char*)Bs[c] + row * 128 + qx);
      }
      __builtin_amdgcn_s_setprio(1);
      #pragma unroll
      for (int mf = 0; mf < 8; ++mf)
        #pragma unroll
        for (int nf = 0; nf < 4; ++nf)
          acc[mf][nf] = __builtin_amdgcn_mfma_f32_16x16x32_bf16(af[mf], bfr[nf], acc[mf][nf], 0, 0, 0);
      __builtin_amdgcn_s_setprio(0);
    }
  }

  #pragma unroll
  for (int nf = 0; nf < 4; ++nf) {
    const int n = (int)bn0 + wc * 64 + nf * 16 + lr;
    const float bv = bias[n];
    #pragma unroll
    for (int mf = 0; mf < 8; ++mf) {
      #pragma unroll
      for (int r = 0; r < 4; ++r) {
        const int m = (int)am0 + wr * 128 + mf * 16 + khi * 4 + r;
        Cb[(long)m * G4_ + n] = bfbits(acc[mf][nf][r] + bv);
      }
    }
  }
}

// ---------------- GEMM3: logits (R13-exact: 256x256, BK=64 2-buf, counted vmcnt) ------
__global__ __launch_bounds__(512, 2) void k_gemm3(
    const unsigned short* __restrict__ A,    // [4096][1024] bf16 (H1 slots 1..64)
    const unsigned short* __restrict__ Bm,   // [32000][1024] bf16 (Wp)
    const float* __restrict__ bias,          // [32000]
    float* __restrict__ out) {               // [64][64][32000] f32
  __shared__ unsigned short As[2][256 * 64];   // 2 x 32 KB
  __shared__ unsigned short Bs[2][256 * 64];   // 2 x 32 KB
  const int tid = threadIdx.x;
  const int wid = tid >> 6, l = tid & 63;
  const int wr = wid >> 2, wc = wid & 3;       // 2M x 4N wave grid
  const int lr = l & 15, khi = l >> 4;
  const int id = blockIdx.x;
  const int by = id / 125, bx = id - by * 125; // R13 decode (best measured)
  const long am0 = (long)by * 256;
  const long bn0 = (long)bx * 256;

  int srow[4], sq[4];
  #pragma unroll
  for (int j = 0; j < 4; ++j) {
    const int idx = j * 512 + tid;
    srow[j] = idx >> 3;
    sq[j] = (idx & 7) ^ (srow[j] & 7);     // pre-swizzled source unit
  }

  f32x4 acc[8][4];
  const f32x4 z = {0.f, 0.f, 0.f, 0.f};
  #pragma unroll
  for (int mf = 0; mf < 8; ++mf)
    #pragma unroll
    for (int nf = 0; nf < 4; ++nf) acc[mf][nf] = z;

  auto stage = [&](int kt, int b) {
    const long koff = (long)kt * 128;      // BK=64 cols * 2B
    #pragma unroll
    for (int j = 0; j < 4; ++j) {
      const int idx = j * 512 + tid;
      gload16((const char*)(A + (am0 + srow[j]) * H_) + koff + sq[j] * 16,
              (char*)As[b] + idx * 16);
    }
    #pragma unroll
    for (int j = 0; j < 4; ++j) {
      const int idx = j * 512 + tid;
      gload16((const char*)(Bm + (bn0 + srow[j]) * H_) + koff + sq[j] * 16,
              (char*)Bs[b] + idx * 16);
    }
  };

  stage(0, 0);
  for (int t = 0; t < 16; ++t) {
    const int c = t & 1;
    __builtin_amdgcn_s_barrier();          // all waves done reading buf c from t-2
    if (t + 1 < 16) {
      stage(t + 1, c ^ 1);
      asm volatile("s_waitcnt vmcnt(8)" ::: "memory");   // tile t done; t+1 in flight
    } else {
      asm volatile("s_waitcnt vmcnt(0)" ::: "memory");
    }
    __builtin_amdgcn_s_barrier();          // tile t staged by ALL waves
    #pragma unroll
    for (int ks = 0; ks < 2; ++ks) {
      const int qx = ((ks * 4 + khi) ^ (lr & 7)) * 16;   // swizzled read unit (bytes)
      bf16x8 af[8], bfr[4];
      #pragma unroll
      for (int mf = 0; mf < 8; ++mf) {
        const int row = wr * 128 + mf * 16 + lr;
        af[mf] = *(const bf16x8*)((const char*)As[c] + row * 128 + qx);
      }
      #pragma unroll
      for (int nf = 0; nf < 4; ++nf) {
        const int row = wc * 64 + nf * 16 + lr;
        bfr[nf] = *(const bf16x8*)((const char*)Bs[c] + row * 128 + qx);
      }
      __builtin_amdgcn_s_setprio(1);
      #pragma unroll
      for (int mf = 0; mf < 8; ++mf)
        #pragma unroll
        for (int nf = 0; nf < 4; ++nf)
          acc[mf][nf] = __builtin_amdgcn_mfma_f32_16x16x32_bf16(af[mf], bfr[nf], acc[mf][nf], 0, 0, 0);
      __builtin_amdgcn_s_setprio(0);
    }
  }

  // epilogue: fp32 nt scatter to out[:,t+1,:]
  #pragma unroll
  for (int nf = 0; nf < 4; ++nf) {
    const int n = (int)bn0 + wc * 64 + nf * 16 + lr;
    const float bv = bias[n];
    #pragma unroll
    for (int mf = 0; mf < 8; ++mf) {
      #pragma unroll
      for (int r = 0; r < 4; ++r) {
        const int m = (int)am0 + wr * 128 + mf * 16 + khi * 4 + r;
        if (m < MROWS) {
          const int t = m >> 6, b = m & 63;
          store_dword_nt(out + (long)(b * T_ + t + 1) * V_ + n, acc[mf][nf][r] + bv);
        }
      }
    }
  }
}

// ---------------- fused 2-layer persistent recurrence (R8-verified lockstep) ----------
__global__ __launch_bounds__(256) void k_fused(
    const unsigned short* __restrict__ Whh0b,  // [4096][1024] bf16
    const unsigned short* __restrict__ Whh1b,  // [4096][1024] bf16
    const unsigned short* __restrict__ Wih1b,  // [4096][1024] bf16
    const unsigned short* __restrict__ Xp,     // [63][64][4096] bf16 (x-proj + b0)
    unsigned short* __restrict__ H0b,          // [65][64][1024] bf16, slot 0 init
    unsigned short* __restrict__ H1b,          // [65][64][1024] bf16, slot 0 init
    const float* __restrict__ c0i, const float* __restrict__ c1i,
    const float* __restrict__ b1s,             // [4096] f32
    unsigned int* __restrict__ f0,             // [64*FPAD]  zeroed
    unsigned int* __restrict__ f1) {           // [128*FPAD] zeroed
  __shared__ unsigned short Wl[64 * 1024];     // 128 KB
  __shared__ __align__(16) float gs1[4][64][8];  // 8 KB (team-1); aliased by team-0
  unsigned short (*hexch)[16] = (unsigned short (*)[16])gs1;

  const int tid = threadIdx.x;
  const int w = tid >> 6, l = tid & 63;
  const int lcol = l & 15, khi = l >> 4;
  const int bw = w * 16;
  const f32x4 z = {0.f, 0.f, 0.f, 0.f};

  if (blockIdx.x < 64) {
    // ================= TEAM 0 : layer 0 =================
    const int blk = blockIdx.x;
    const int jb = blk << 4;
    for (int u = tid; u < 64 * 128; u += 256) {
      const int rr = u >> 7, cu = u & 127;
      const int g = rr >> 4, jj = rr & 15;
      ((bf16x8*)Wl)[rr * 128 + (cu ^ (rr & 7))] =
          *(const bf16x8*)(Whh0b + (size_t)(g * 1024 + jb + jj) * H_ + cu * 8);
    }
    f32x4 cr;
    #pragma unroll
    for (int r = 0; r < 4; ++r)
      cr[r] = c0i[(size_t)(bw + khi * 4 + r) * H_ + jb + lcol];
    unsigned short pin[16];
    #pragma unroll
    for (int r = 0; r < 4; ++r) {
      const unsigned short* ir = Xp + (size_t)(bw + khi * 4 + r) * G4_ + jb + lcol;
      pin[r * 4 + 0] = ir[0];
      pin[r * 4 + 1] = ir[H_];
      pin[r * 4 + 2] = ir[2 * H_];
      pin[r * 4 + 3] = ir[3 * H_];
    }
    __syncthreads();

    for (int s = 0; s < TS_; ++s) {
      if (s > 0) {
        if (tid < 64)
          while (load_dword_dc(&f0[tid << 5]) < (unsigned)s) __builtin_amdgcn_s_sleep(1);
        __syncthreads();
      }
      f32x4 a0, a1, a2, a3;
      #pragma unroll
      for (int r = 0; r < 4; ++r) {
        a0[r] = bf2f(pin[r * 4 + 0]);
        a1[r] = bf2f(pin[r * 4 + 1]);
        a2[r] = bf2f(pin[r * 4 + 2]);
        a3[r] = bf2f(pin[r * 4 + 3]);
      }
      const unsigned short* hrow = H0b + (size_t)s * BH + (size_t)(bw + lcol) * H_ + khi * 8;
      #pragma unroll 8
      for (int kk = 0; kk < 32; ++kk) {
        const bf16x8 av = *(const bf16x8*)(hrow + kk * 32);
        const int un = (kk * 4 + khi) ^ (lcol & 7);
        const bf16x8 b0 = ((const bf16x8*)Wl)[(0 * 16 + lcol) * 128 + un];
        const bf16x8 b1 = ((const bf16x8*)Wl)[(1 * 16 + lcol) * 128 + un];
        const bf16x8 b2 = ((const bf16x8*)Wl)[(2 * 16 + lcol) * 128 + un];
        const bf16x8 b3 = ((const bf16x8*)Wl)[(3 * 16 + lcol) * 128 + un];
        a0 = __builtin_amdgcn_mfma_f32_16x16x32_bf16(av, b0, a0, 0, 0, 0);
        a1 = __builtin_amdgcn_mfma_f32_16x16x32_bf16(av, b1, a1, 0, 0, 0);
        a2 = __builtin_amdgcn_mfma_f32_16x16x32_bf16(av, b2, a2, 0, 0, 0);
        a3 = __builtin_amdgcn_mfma_f32_16x16x32_bf16(av, b3, a3, 0, 0, 0);
      }
      #pragma unroll
      for (int r = 0; r < 4; ++r) {
        const float gi = fsig(a0[r]);
        const float gf = fsig(a1[r]);
        const float gg = ftanh(a2[r]);
        const float go = fsig(a3[r]);
        cr[r] = gf * cr[r] + gi * gg;
        hexch[bw + khi * 4 + r][lcol] = bfbits(go * ftanh(cr[r]));
      }
      if (s + 1 < TS_) {
        const unsigned short* inb = Xp + (size_t)(s + 1) * (B_ * G4_);
        #pragma unroll
        for (int r = 0; r < 4; ++r) {
          const unsigned short* ir = inb + (size_t)(bw + khi * 4 + r) * G4_ + jb + lcol;
          pin[r * 4 + 0] = ir[0];
          pin[r * 4 + 1] = ir[H_];
          pin[r * 4 + 2] = ir[2 * H_];
          pin[r * 4 + 3] = ir[3 * H_];
        }
      }
      __syncthreads();                       // hexch complete
      if (tid < 128) {                       // coalesced 16B device-coherent stores
        const int b = tid >> 1, hf = tid & 1;
        const uint32x4 v = *(const uint32x4*)&hexch[b][hf * 8];
        store_b128_dc(H0b + (size_t)(s + 1) * BH + (size_t)b * H_ + jb + hf * 8, v);
      }
      __syncthreads();                       // drain stores (per-wave vmcnt)
      if (tid == 0) store_dword_dc(&f0[blk << 5], (unsigned)(s + 1));
    }
  } else {
    // ================= TEAM 1 : layer 1 =================
    const int blk1 = blockIdx.x - 64;
    const int jb1 = blk1 << 3;
    for (int u = tid; u < 64 * 128; u += 256) {
      const int pr = u >> 7, cu = u & 127;
      const int prl = pr & 31, tt = prl >> 4, lr_ = prl & 15;
      const int g = tt * 2 + (lr_ >> 3), jj = lr_ & 7;
      const unsigned short* src =
          ((pr >> 5) ? Wih1b : Whh1b) + (size_t)(g * 1024 + jb1 + jj) * H_ + cu * 8;
      ((bf16x8*)Wl)[pr * 128 + (cu ^ (pr & 7))] = *(const bf16x8*)src;
    }
    const int bb = tid >> 2;
    const int j0 = (tid * 2) & 7;
    float cA = c1i[(size_t)bb * H_ + jb1 + j0];
    float cB = c1i[(size_t)bb * H_ + jb1 + j0 + 1];
    float biA[4], biB[4];
    #pragma unroll
    for (int g = 0; g < 4; ++g) {
      biA[g] = b1s[g * 1024 + jb1 + j0];
      biB[g] = b1s[g * 1024 + jb1 + j0 + 1];
    }
    __syncthreads();

    for (int s = 1; s <= TS_; ++s) {
      {
        const unsigned t0 = (unsigned)s, t1 = (unsigned)(s - 1);
        if (tid < 64) {
          while (load_dword_dc(&f0[tid << 5]) < t0) __builtin_amdgcn_s_sleep(1);
        } else if (tid < 192) {
          while (load_dword_dc(&f1[(tid - 64) << 5]) < t1) __builtin_amdgcn_s_sleep(1);
        }
        __syncthreads();
      }
      f32x4 ac0 = z, ac1 = z;
      const unsigned short* a1p = H1b + (size_t)(s - 1) * BH + (size_t)(bw + lcol) * H_ + khi * 8;
      const unsigned short* a0p = H0b + (size_t)s * BH + (size_t)(bw + lcol) * H_ + khi * 8;
      #pragma unroll 8
      for (int kk = 0; kk < 32; ++kk) {
        const bf16x8 av = *(const bf16x8*)(a1p + kk * 32);
        const int un = (kk * 4 + khi) ^ (lcol & 7);
        const bf16x8 b0 = ((const bf16x8*)Wl)[(0 + lcol) * 128 + un];
        const bf16x8 b1 = ((const bf16x8*)Wl)[(16 + lcol) * 128 + un];
        ac0 = __builtin_amdgcn_mfma_f32_16x16x32_bf16(av, b0, ac0, 0, 0, 0);
        ac1 = __builtin_amdgcn_mfma_f32_16x16x32_bf16(av, b1, ac1, 0, 0, 0);
      }
      #pragma unroll 8
      for (int kk = 0; kk < 32; ++kk) {
        const bf16x8 av = *(const bf16x8*)(a0p + kk * 32);
        const int un = (kk * 4 + khi) ^ (lcol & 7);
        const bf16x8 b0 = ((const bf16x8*)Wl)[(32 + lcol) * 128 + un];
        const bf16x8 b1 = ((const bf16x8*)Wl)[(48 + lcol) * 128 + un];
        ac0 = __builtin_amdgcn_mfma_f32_16x16x32_bf16(av, b0, ac0, 0, 0, 0);
        ac1 = __builtin_amdgcn_mfma_f32_16x16x32_bf16(av, b1, ac1, 0, 0, 0);
      }
      #pragma unroll
      for (int r = 0; r < 4; ++r) {
        const int b = bw + khi * 4 + r;
        gs1[lcol >> 3][b][lcol & 7] = ac0[r];
        gs1[2 + (lcol >> 3)][b][lcol & 7] = ac1[r];
      }
      __syncthreads();
      {
        const float giA = fsig(gs1[0][bb][j0] + biA[0]);
        const float gfA = fsig(gs1[1][bb][j0] + biA[1]);
        const float ggA = ftanh(gs1[2][bb][j0] + biA[2]);
        const float goA = fsig(gs1[3][bb][j0] + biA[3]);
        cA = gfA * cA + giA * ggA;
        const unsigned short hA = bfbits(goA * ftanh(cA));
        const float giB = fsig(gs1[0][bb][j0 + 1] + biB[0]);
        const float gfB = fsig(gs1[1][bb][j0 + 1] + biB[1]);
        const float ggB = ftanh(gs1[2][bb][j0 + 1] + biB[2]);
        const float goB = fsig(gs1[3][bb][j0 + 1] + biB[3]);
        cB = gfB * cB + giB * ggB;
        const unsigned short hB = bfbits(goB * ftanh(cB));
        const unsigned int hv = ((unsigned int)hB << 16) | hA;
        store_dword_dc(H1b + (size_t)s * BH + (size_t)bb * H_ + jb1 + j0, hv);
      }
      __syncthreads();                       // drain stores + gs1 WAR protection
      if (tid == 0) store_dword_dc(&f1[blk1 << 5], (unsigned)s);
    }
  }
}

// ---------------- launch ----------------

extern "C" void kernel_launch(void* const* d_in, const int* in_sizes, int n_in,
                              void* d_out, int out_size, void* d_ws, size_t ws_size,
                              hipStream_t stream) {
  (void)in_sizes; (void)n_in; (void)out_size; (void)ws_size;
  const float* hidden = (const float*)d_in[0];
  const float* cell   = (const float*)d_in[1];
  const int*   caps   = (const int*)d_in[2];
  const float* embed  = (const float*)d_in[3];
  const float* Wih0   = (const float*)d_in[4];
  const float* Whh0   = (const float*)d_in[5];
  const float* bih0   = (const float*)d_in[6];
  const float* bhh0   = (const float*)d_in[7];
  const float* Wih1   = (const float*)d_in[8];
  const float* Whh1   = (const float*)d_in[9];
  const float* bih1   = (const float*)d_in[10];
  const float* bhh1   = (const float*)d_in[11];
  const float* Wp     = (const float*)d_in[12];
  const float* bp     = (const float*)d_in[13];
  float* out = (float*)d_out;

  // workspace layout (~150 MB)
  char* p = (char*)d_ws;
  auto alloc = [&](size_t bytes) { char* r = p; p += (bytes + 255) & ~(size_t)255; return r; };
  unsigned short* Xbf   = (unsigned short*)alloc((size_t)MPAD * E_ * 2);
  unsigned short* Wih0b = (unsigned short*)alloc((size_t)G4_ * E_ * 2);
  unsigned short* Whh0b = (unsigned short*)alloc((size_t)G4_ * H_ * 2);
  unsigned short* Wih1b = (unsigned short*)alloc((size_t)G4_ * H_ * 2);
  unsigned short* Whh1b = (unsigned short*)alloc((size_t)G4_ * H_ * 2);
  unsigned short* Wpb   = (unsigned short*)alloc((size_t)V_ * H_ * 2);
  unsigned short* Xp    = (unsigned short*)alloc((size_t)MPAD * G4_ * 2);
  unsigned short* H0    = (unsigned short*)alloc((size_t)(MPAD + B_) * H_ * 2);  // slots 0..64
  unsigned short* H1    = (unsigned short*)alloc((size_t)(MPAD + B_) * H_ * 2);
  float* c0  = (float*)alloc((size_t)B_ * H_ * 4);
  float* c1  = (float*)alloc((size_t)B_ * H_ * 4);
  float* b0s = (float*)alloc((size_t)G4_ * 4);
  float* b1s = (float*)alloc((size_t)G4_ * 4);
  unsigned int* cbar = (unsigned int*)alloc((size_t)192 * FPAD * 4);  // f0 | f1, padded

  k_castW<<<4096, 256, 0, stream>>>((const float4*)Wih0, (const float4*)Whh0,
                                    (const float4*)Wih1, (const float4*)Whh1,
                                    (ushort4*)Wih0b, (ushort4*)Whh0b,
                                    (ushort4*)Wih1b, (ushort4*)Whh1b);
  k_cast4<<<4096, 256, 0, stream>>>((const float4*)Wp, (ushort4*)Wpb, V_ * H_ / 4);
  k_bias2<<<32, 256, 0, stream>>>(bih0, bhh0, bih1, bhh1, b0s, b1s);
  k_gather<<<2048, 256, 0, stream>>>(embed, caps, Xbf);
  k_init<<<512, 256, 0, stream>>>(hidden, cell, H0, H1, c0, c1, cbar);
  k_zero_t0<<<2000, 256, 0, stream>>>((float4*)out);

  // GEMM1: Xp = X @ W_ih0^T + b0   (M=4096, N=4096, K=512; 256^2 proven structure)
  k_gemm1<<<dim3(16, 16), 512, 0, stream>>>(Xbf, Wih0b, b0s, Xp);

  // fused 2-layer recurrence (192 co-resident blocks, R8-verified lockstep)
  k_fused<<<192, 256, 0, stream>>>(Whh0b, Whh1b, Wih1b, Xp, H0, H1, c0, c1, b1s,
                                   cbar, cbar + 64 * FPAD);

  // GEMM3: logits = H1[1..63] @ Wp^T + bp -> out[:,1:,:]  (R13-exact 256^2, BK=64)
  k_gemm3<<<2000, 512, 0, stream>>>(H1 + (size_t)B_ * H_, Wpb, bp, out);
}